// Round 6
// baseline (225.209 us; speedup 1.0000x reference)
//
#include <hip/hip_runtime.h>
#include <hip/hip_bf16.h>
#include <math.h>

// CovidModel forward, closed form:
//   A[d][s] = wA[s] * 2^(L[d]/T_serial[s]),  L[d] = inclusive prefix of log2 r
//   M[d][s] = rho[s] * sum_j pi[j][s] * A_ext[J+d-j-1][s]
// Rescaled: Ã = A/wA, pis[j] = rho*wA*pi[j] → M = Σ_j pis[j]·Ã[d-1-j],
// Ã[d] = exp2(L[d]·invT): one v_exp_f32 per (day,sample).
//
// TWO kernels total:
//   k1 scan_blocks: per-1024-block inclusive fp64 scan of log2(r) via wave
//      shfl scans (2 barriers); emits Lpart (fp64, block-local) + blockSums.
//   k2 forecast4: prologue shfl-scans the <=64 blockSums into a 512 B LDS
//      exclusive-offset table; every L access is (float)(Lpart[t]+offSh[t>>10]).
// Forecast: thread = 4 samples × 40-day chunk (50000/40 = 1250 blocks exact);
// per-10-day group prefetches 10 uniform L values ahead of the exp2 chain;
// compile-time rotated 10-register window; __launch_bounds__(256).
//
// This round (isolating the two forecast-internal paths never A/B'd):
//  - NT float4 stores restored (round 0 removed them confounded with
//    launch_bounds; output is write-once never-read → bypass L2 allocation).
//  - exp2f → __builtin_amdgcn_exp2f (raw v_exp_f32; inputs bounded |x|<~2,
//    no denormal range, absmax tol 0.5 on O(100) values — safe; drops the
//    OCML fixup instructions around 50M exp2 calls).

#define SCAN_BS 1024

typedef float v4f __attribute__((ext_vector_type(4)));

__global__ __launch_bounds__(SCAN_BS)
void scan_blocks_kernel(const float* __restrict__ r, int T,
                        double* __restrict__ Lpart,
                        double* __restrict__ blockSums) {
    __shared__ double waveSums[16];
    const int i    = blockIdx.x * SCAN_BS + threadIdx.x;
    const int lane = threadIdx.x & 63;
    const int wid  = threadIdx.x >> 6;

    double v = (i < T) ? (double)log2f(r[i]) : 0.0;
    // inclusive wave scan (6 shuffle steps)
#pragma unroll
    for (int off = 1; off < 64; off <<= 1) {
        double u = __shfl_up(v, (unsigned)off, 64);
        if (lane >= off) v += u;
    }
    if (lane == 63) waveSums[wid] = v;
    __syncthreads();
    if (wid == 0) {
        double w = (lane < 16) ? waveSums[lane] : 0.0;
#pragma unroll
        for (int off = 1; off < 16; off <<= 1) {
            double u = __shfl_up(w, (unsigned)off, 64);
            if (lane >= off) w += u;
        }
        if (lane < 16) waveSums[lane] = w;           // inclusive wave prefixes
    }
    __syncthreads();
    if (wid > 0) v += waveSums[wid - 1];
    if (i < T) Lpart[i] = v;                          // block-local inclusive
    if (threadIdx.x == SCAN_BS - 1) blockSums[blockIdx.x] = v;
}

template <int J, bool CHECK>
__global__ __launch_bounds__(256)
void forecast4_kernel(const double* __restrict__ Lpart,
                      const double* __restrict__ blockSums, int nb,
                      const float* __restrict__ warmup_A,
                      const float* __restrict__ T_serial,
                      const float* __restrict__ rho_M,
                      const float* __restrict__ pi_M,
                      float* __restrict__ out,
                      int d0_base, int T, int S, int dchunk) {
    // ---- prologue: exclusive scan-block offsets into LDS (nb <= 64) ----
    __shared__ double offSh[64];
    if (threadIdx.x < 64) {
        const int lane = (int)threadIdx.x;
        double v = (lane < nb) ? blockSums[lane] : 0.0;
#pragma unroll
        for (int off = 1; off < 64; off <<= 1) {
            double u = __shfl_up(v, (unsigned)off, 64);
            if (lane >= off) v += u;
        }
        double excl = __shfl_up(v, 1u, 64);
        if (lane == 0) excl = 0.0;
        offSh[lane] = excl;
    }
    __syncthreads();

    const int q = blockIdx.x * blockDim.x + threadIdx.x;
    const int s = q * 4;
    if (s + 3 >= S) return;                  // full quads only (tail via scalar kernel)

    const int d0   = d0_base + blockIdx.y * dchunk;
    const int dend = CHECK ? min(d0 + dchunk, T) : (d0 + dchunk);

    // L(t) = Lpart[t] + offSh[t>>10], emitted as fp32
#define LVAL(t) ((float)(Lpart[(t)] + offSh[(t) >> 10]))

    const float4 ts  = *reinterpret_cast<const float4*>(&T_serial[s]);
    const float4 rho = *reinterpret_cast<const float4*>(&rho_M[s]);
    const float4 wA4 = *reinterpret_cast<const float4*>(&warmup_A[(J - 1) * S + s]);

    float invT[4] = {1.f / ts.x, 1.f / ts.y, 1.f / ts.z, 1.f / ts.w};
    float wA[4]   = {wA4.x, wA4.y, wA4.z, wA4.w};
    float scl[4]  = {rho.x * wA[0], rho.y * wA[1], rho.z * wA[2], rho.w * wA[3]};
    float invW[4] = {1.f / wA[0], 1.f / wA[1], 1.f / wA[2], 1.f / wA[3]};

    float pis[J][4];
#pragma unroll
    for (int j = 0; j < J; ++j) {
        const float4 p = *reinterpret_cast<const float4*>(&pi_M[j * S + s]);
        pis[j][0] = p.x * scl[0]; pis[j][1] = p.y * scl[1];
        pis[j][2] = p.z * scl[2]; pis[j][3] = p.w * scl[3];
    }

    // Invariant at group start db: a[i][c] = Ã[db - J + i], i = 0..J-1.
    float a[J][4];
#pragma unroll
    for (int i = 0; i < J; ++i) {
        const int t = d0 - J + i;
        if (t >= 0) {
            const float Lt = LVAL(t);
#pragma unroll
            for (int c = 0; c < 4; ++c) a[i][c] = __builtin_amdgcn_exp2f(Lt * invT[c]);
        } else {
            const float4 w = *reinterpret_cast<const float4*>(&warmup_A[(J + t) * S + s]);
            a[i][0] = w.x * invW[0]; a[i][1] = w.y * invW[1];
            a[i][2] = w.z * invW[2]; a[i][3] = w.w * invW[3];
        }
    }

    for (int db = d0; db < dend; db += J) {
        // Prefetch the group's J uniform L values (hoists/batches the loads
        // ahead of the dependent exp2 chain).
        float Lg[J];
        if (!CHECK) {
#pragma unroll
            for (int k = 0; k < J; ++k) Lg[k] = LVAL(db + k);
        } else {
#pragma unroll
            for (int k = 0; k < J; ++k) Lg[k] = (db + k < T) ? LVAL(db + k) : 0.0f;
        }
#pragma unroll
        for (int k = 0; k < J; ++k) {
            const int d = db + k;
            if (!CHECK || d < dend) {
                float m[4] = {0.f, 0.f, 0.f, 0.f};
#pragma unroll
                for (int j = 0; j < J; ++j) {
                    const int slot = (J + k - 1 - j) % J;    // compile-time
#pragma unroll
                    for (int c = 0; c < 4; ++c) m[c] = fmaf(pis[j][c], a[slot][c], m[c]);
                }
                v4f mv;
                mv.x = m[0]; mv.y = m[1]; mv.z = m[2]; mv.w = m[3];
                __builtin_nontemporal_store(mv,
                    reinterpret_cast<v4f*>(&out[(size_t)d * S + s]));
#pragma unroll
                for (int c = 0; c < 4; ++c) a[k][c] = __builtin_amdgcn_exp2f(Lg[k] * invT[c]);
            }
        }
    }
#undef LVAL
}

template <int J>
__global__ __launch_bounds__(64)
void forecast_scalar_kernel(const double* __restrict__ Lpart,
                            const double* __restrict__ blockSums, int nb,
                            const float* __restrict__ warmup_A,
                            const float* __restrict__ T_serial,
                            const float* __restrict__ rho_M,
                            const float* __restrict__ pi_M,
                            float* __restrict__ out,
                            int T, int S, int s0, int dchunk) {
    __shared__ double offSh[64];
    {
        const int lane = (int)threadIdx.x;   // 64-thread blocks
        double v = (lane < nb) ? blockSums[lane] : 0.0;
#pragma unroll
        for (int off = 1; off < 64; off <<= 1) {
            double u = __shfl_up(v, (unsigned)off, 64);
            if (lane >= off) v += u;
        }
        double excl = __shfl_up(v, 1u, 64);
        if (lane == 0) excl = 0.0;
        offSh[lane] = excl;
    }
    __syncthreads();

    const int s = s0 + blockIdx.x * blockDim.x + threadIdx.x;
    if (s >= S) return;
    const int d0   = blockIdx.y * dchunk;
    const int dend = min(d0 + dchunk, T);

#define LVAL(t) ((float)(Lpart[(t)] + offSh[(t) >> 10]))

    const float invT = 1.0f / T_serial[s];
    const float wA   = warmup_A[(J - 1) * S + s];
    const float scl  = rho_M[s] * wA;
    const float invW = 1.0f / wA;

    float pis[J];
#pragma unroll
    for (int j = 0; j < J; ++j) pis[j] = pi_M[j * S + s] * scl;

    float a[J];
#pragma unroll
    for (int i = 0; i < J; ++i) {
        const int t = d0 - J + i;
        a[i] = (t >= 0) ? __builtin_amdgcn_exp2f(LVAL(t) * invT)
                        : warmup_A[(J + t) * S + s] * invW;
    }
    for (int db = d0; db < dend; db += J) {
#pragma unroll
        for (int k = 0; k < J; ++k) {
            const int d = db + k;
            if (d < dend) {
                float m = 0.0f;
#pragma unroll
                for (int j = 0; j < J; ++j) m = fmaf(pis[j], a[(J + k - 1 - j) % J], m);
                __builtin_nontemporal_store(m, &out[(size_t)d * S + s]);
                a[k] = __builtin_amdgcn_exp2f(LVAL(d) * invT);
            }
        }
    }
#undef LVAL
}

extern "C" void kernel_launch(void* const* d_in, const int* in_sizes, int n_in,
                              void* d_out, int out_size, void* d_ws, size_t ws_size,
                              hipStream_t stream) {
    const float* r_t      = (const float*)d_in[0];   // (1, T)
    const float* warmup_A = (const float*)d_in[1];   // (J, S)
    const float* T_serial = (const float*)d_in[2];   // (S,)
    const float* rho_M    = (const float*)d_in[3];   // (S,)
    const float* pi_M     = (const float*)d_in[4];   // (J, S)
    float* out            = (float*)d_out;           // (T, S)

    const int T = in_sizes[0];
    const int S = in_sizes[2];
    const int nb = (T + SCAN_BS - 1) / SCAN_BS;      // 49 for T=50000 (<=64)

    // Workspace layout
    char* ws = (char*)d_ws;
    double* Lpart = (double*)ws;                              // T doubles
    double* bsums = (double*)(ws + ((size_t)T * 8 + 255) / 256 * 256);  // 64

    scan_blocks_kernel<<<nb, SCAN_BS, 0, stream>>>(r_t, T, Lpart, bsums);

    const int dchunk = 40;                            // multiple of J=10; 50000/40=1250 exact
    const int quads = S / 4;
    const int fullChunks = T / dchunk;                // 1250 for T=50000
    const int dTailStart = fullChunks * dchunk;       // == T here (no ragged tail)

    if (quads > 0) {
        dim3 block(256, 1, 1);
        if (fullChunks > 0) {
            dim3 grid((quads + 255) / 256, fullChunks, 1);
            forecast4_kernel<10, false><<<grid, block, 0, stream>>>(
                Lpart, bsums, nb, warmup_A, T_serial, rho_M, pi_M, out, 0, T, S, dchunk);
        }
        if (dTailStart < T) {
            dim3 grid((quads + 255) / 256, 1, 1);
            forecast4_kernel<10, true><<<grid, block, 0, stream>>>(
                Lpart, bsums, nb, warmup_A, T_serial, rho_M, pi_M, out, dTailStart, T, S, dchunk);
        }
    }
    const int tail = S - quads * 4;
    if (tail > 0) {
        dim3 block(64, 1, 1);
        dim3 grid(1, (T + dchunk - 1) / dchunk, 1);
        forecast_scalar_kernel<10><<<grid, block, 0, stream>>>(
            Lpart, bsums, nb, warmup_A, T_serial, rho_M, pi_M, out, T, S,
            quads * 4, dchunk);
    }
}

// Round 7
// 209.166 us; speedup vs baseline: 1.0767x; 1.0767x over previous
//
#include <hip/hip_runtime.h>
#include <hip/hip_bf16.h>
#include <math.h>

// CovidModel forward, closed form:
//   A[d][s] = wA[s] * 2^(L[d]/T_serial[s]),  L[d] = inclusive prefix of log2 r
//   M[d][s] = rho[s] * sum_j pi[j][s] * A_ext[J+d-j-1][s]
// Rescaled: Ã = A/wA, pis[j] = rho*wA*pi[j] → M = Σ_j pis[j]·Ã[d-1-j],
// Ã[d] = exp2(L[d]·invT): one v_exp_f32 per (day,sample).
//
// TWO kernels total:
//   k1 scan_blocks: per-1024-block inclusive fp64 scan of log2(r) via wave
//      shfl scans (2 barriers); emits Lpart (fp64, block-local) + blockSums.
//   k2 forecast4: prologue shfl-scans the <=64 blockSums into a 512 B LDS
//      exclusive-offset table; every L access is (float)(Lpart[t]+offSh[t>>10]).
// Forecast: thread = 4 samples × 100-day chunk (50000/100 = 500 blocks exact,
// busiest-CU schedule 2×(setup+100·work) vs 5×(setup+40·work) at dchunk=40 —
// amortizes the ~2000-cycle per-block setup; ~7.8 waves/CU still ≥4× what the
// store pipe needs); per-10-day group prefetches 10 uniform L values ahead of
// the exp2 chain; compile-time rotated 10-register window; __launch_bounds__(256).
//
// Measured A/B history:
//  - NT stores: +16 µs regression (round 6) — REVERTED to plain float4
//    write-back stores (the 6.3-6.6 TB/s fill ceiling is the write-back path).
//  - exp2f → __builtin_amdgcn_exp2f: kept (strictly fewer instructions; inputs
//    bounded |x|≲2, no denormal range, absmax tol 0.5 — safe).

#define SCAN_BS 1024

typedef float v4f __attribute__((ext_vector_type(4)));

__global__ __launch_bounds__(SCAN_BS)
void scan_blocks_kernel(const float* __restrict__ r, int T,
                        double* __restrict__ Lpart,
                        double* __restrict__ blockSums) {
    __shared__ double waveSums[16];
    const int i    = blockIdx.x * SCAN_BS + threadIdx.x;
    const int lane = threadIdx.x & 63;
    const int wid  = threadIdx.x >> 6;

    double v = (i < T) ? (double)log2f(r[i]) : 0.0;
    // inclusive wave scan (6 shuffle steps)
#pragma unroll
    for (int off = 1; off < 64; off <<= 1) {
        double u = __shfl_up(v, (unsigned)off, 64);
        if (lane >= off) v += u;
    }
    if (lane == 63) waveSums[wid] = v;
    __syncthreads();
    if (wid == 0) {
        double w = (lane < 16) ? waveSums[lane] : 0.0;
#pragma unroll
        for (int off = 1; off < 16; off <<= 1) {
            double u = __shfl_up(w, (unsigned)off, 64);
            if (lane >= off) w += u;
        }
        if (lane < 16) waveSums[lane] = w;           // inclusive wave prefixes
    }
    __syncthreads();
    if (wid > 0) v += waveSums[wid - 1];
    if (i < T) Lpart[i] = v;                          // block-local inclusive
    if (threadIdx.x == SCAN_BS - 1) blockSums[blockIdx.x] = v;
}

template <int J, bool CHECK>
__global__ __launch_bounds__(256)
void forecast4_kernel(const double* __restrict__ Lpart,
                      const double* __restrict__ blockSums, int nb,
                      const float* __restrict__ warmup_A,
                      const float* __restrict__ T_serial,
                      const float* __restrict__ rho_M,
                      const float* __restrict__ pi_M,
                      float* __restrict__ out,
                      int d0_base, int T, int S, int dchunk) {
    // ---- prologue: exclusive scan-block offsets into LDS (nb <= 64) ----
    __shared__ double offSh[64];
    if (threadIdx.x < 64) {
        const int lane = (int)threadIdx.x;
        double v = (lane < nb) ? blockSums[lane] : 0.0;
#pragma unroll
        for (int off = 1; off < 64; off <<= 1) {
            double u = __shfl_up(v, (unsigned)off, 64);
            if (lane >= off) v += u;
        }
        double excl = __shfl_up(v, 1u, 64);
        if (lane == 0) excl = 0.0;
        offSh[lane] = excl;
    }
    __syncthreads();

    const int q = blockIdx.x * blockDim.x + threadIdx.x;
    const int s = q * 4;
    if (s + 3 >= S) return;                  // full quads only (tail via scalar kernel)

    const int d0   = d0_base + blockIdx.y * dchunk;
    const int dend = CHECK ? min(d0 + dchunk, T) : (d0 + dchunk);

    // L(t) = Lpart[t] + offSh[t>>10], emitted as fp32
#define LVAL(t) ((float)(Lpart[(t)] + offSh[(t) >> 10]))

    const float4 ts  = *reinterpret_cast<const float4*>(&T_serial[s]);
    const float4 rho = *reinterpret_cast<const float4*>(&rho_M[s]);
    const float4 wA4 = *reinterpret_cast<const float4*>(&warmup_A[(J - 1) * S + s]);

    float invT[4] = {1.f / ts.x, 1.f / ts.y, 1.f / ts.z, 1.f / ts.w};
    float wA[4]   = {wA4.x, wA4.y, wA4.z, wA4.w};
    float scl[4]  = {rho.x * wA[0], rho.y * wA[1], rho.z * wA[2], rho.w * wA[3]};
    float invW[4] = {1.f / wA[0], 1.f / wA[1], 1.f / wA[2], 1.f / wA[3]};

    float pis[J][4];
#pragma unroll
    for (int j = 0; j < J; ++j) {
        const float4 p = *reinterpret_cast<const float4*>(&pi_M[j * S + s]);
        pis[j][0] = p.x * scl[0]; pis[j][1] = p.y * scl[1];
        pis[j][2] = p.z * scl[2]; pis[j][3] = p.w * scl[3];
    }

    // Invariant at group start db: a[i][c] = Ã[db - J + i], i = 0..J-1.
    float a[J][4];
#pragma unroll
    for (int i = 0; i < J; ++i) {
        const int t = d0 - J + i;
        if (t >= 0) {
            const float Lt = LVAL(t);
#pragma unroll
            for (int c = 0; c < 4; ++c) a[i][c] = __builtin_amdgcn_exp2f(Lt * invT[c]);
        } else {
            const float4 w = *reinterpret_cast<const float4*>(&warmup_A[(J + t) * S + s]);
            a[i][0] = w.x * invW[0]; a[i][1] = w.y * invW[1];
            a[i][2] = w.z * invW[2]; a[i][3] = w.w * invW[3];
        }
    }

    for (int db = d0; db < dend; db += J) {
        // Prefetch the group's J uniform L values (hoists/batches the loads
        // ahead of the dependent exp2 chain).
        float Lg[J];
        if (!CHECK) {
#pragma unroll
            for (int k = 0; k < J; ++k) Lg[k] = LVAL(db + k);
        } else {
#pragma unroll
            for (int k = 0; k < J; ++k) Lg[k] = (db + k < T) ? LVAL(db + k) : 0.0f;
        }
#pragma unroll
        for (int k = 0; k < J; ++k) {
            const int d = db + k;
            if (!CHECK || d < dend) {
                float m[4] = {0.f, 0.f, 0.f, 0.f};
#pragma unroll
                for (int j = 0; j < J; ++j) {
                    const int slot = (J + k - 1 - j) % J;    // compile-time
#pragma unroll
                    for (int c = 0; c < 4; ++c) m[c] = fmaf(pis[j][c], a[slot][c], m[c]);
                }
                v4f mv;
                mv.x = m[0]; mv.y = m[1]; mv.z = m[2]; mv.w = m[3];
                *reinterpret_cast<v4f*>(&out[(size_t)d * S + s]) = mv;
#pragma unroll
                for (int c = 0; c < 4; ++c) a[k][c] = __builtin_amdgcn_exp2f(Lg[k] * invT[c]);
            }
        }
    }
#undef LVAL
}

template <int J>
__global__ __launch_bounds__(64)
void forecast_scalar_kernel(const double* __restrict__ Lpart,
                            const double* __restrict__ blockSums, int nb,
                            const float* __restrict__ warmup_A,
                            const float* __restrict__ T_serial,
                            const float* __restrict__ rho_M,
                            const float* __restrict__ pi_M,
                            float* __restrict__ out,
                            int T, int S, int s0, int dchunk) {
    __shared__ double offSh[64];
    {
        const int lane = (int)threadIdx.x;   // 64-thread blocks
        double v = (lane < nb) ? blockSums[lane] : 0.0;
#pragma unroll
        for (int off = 1; off < 64; off <<= 1) {
            double u = __shfl_up(v, (unsigned)off, 64);
            if (lane >= off) v += u;
        }
        double excl = __shfl_up(v, 1u, 64);
        if (lane == 0) excl = 0.0;
        offSh[lane] = excl;
    }
    __syncthreads();

    const int s = s0 + blockIdx.x * blockDim.x + threadIdx.x;
    if (s >= S) return;
    const int d0   = blockIdx.y * dchunk;
    const int dend = min(d0 + dchunk, T);

#define LVAL(t) ((float)(Lpart[(t)] + offSh[(t) >> 10]))

    const float invT = 1.0f / T_serial[s];
    const float wA   = warmup_A[(J - 1) * S + s];
    const float scl  = rho_M[s] * wA;
    const float invW = 1.0f / wA;

    float pis[J];
#pragma unroll
    for (int j = 0; j < J; ++j) pis[j] = pi_M[j * S + s] * scl;

    float a[J];
#pragma unroll
    for (int i = 0; i < J; ++i) {
        const int t = d0 - J + i;
        a[i] = (t >= 0) ? __builtin_amdgcn_exp2f(LVAL(t) * invT)
                        : warmup_A[(J + t) * S + s] * invW;
    }
    for (int db = d0; db < dend; db += J) {
#pragma unroll
        for (int k = 0; k < J; ++k) {
            const int d = db + k;
            if (d < dend) {
                float m = 0.0f;
#pragma unroll
                for (int j = 0; j < J; ++j) m = fmaf(pis[j], a[(J + k - 1 - j) % J], m);
                out[(size_t)d * S + s] = m;
                a[k] = __builtin_amdgcn_exp2f(LVAL(d) * invT);
            }
        }
    }
#undef LVAL
}

extern "C" void kernel_launch(void* const* d_in, const int* in_sizes, int n_in,
                              void* d_out, int out_size, void* d_ws, size_t ws_size,
                              hipStream_t stream) {
    const float* r_t      = (const float*)d_in[0];   // (1, T)
    const float* warmup_A = (const float*)d_in[1];   // (J, S)
    const float* T_serial = (const float*)d_in[2];   // (S,)
    const float* rho_M    = (const float*)d_in[3];   // (S,)
    const float* pi_M     = (const float*)d_in[4];   // (J, S)
    float* out            = (float*)d_out;           // (T, S)

    const int T = in_sizes[0];
    const int S = in_sizes[2];
    const int nb = (T + SCAN_BS - 1) / SCAN_BS;      // 49 for T=50000 (<=64)

    // Workspace layout
    char* ws = (char*)d_ws;
    double* Lpart = (double*)ws;                              // T doubles
    double* bsums = (double*)(ws + ((size_t)T * 8 + 255) / 256 * 256);  // 64

    scan_blocks_kernel<<<nb, SCAN_BS, 0, stream>>>(r_t, T, Lpart, bsums);

    const int dchunk = 100;                           // multiple of J=10; 50000/100=500 exact
    const int quads = S / 4;
    const int fullChunks = T / dchunk;                // 500 for T=50000
    const int dTailStart = fullChunks * dchunk;       // == T here (no ragged tail)

    if (quads > 0) {
        dim3 block(256, 1, 1);
        if (fullChunks > 0) {
            dim3 grid((quads + 255) / 256, fullChunks, 1);
            forecast4_kernel<10, false><<<grid, block, 0, stream>>>(
                Lpart, bsums, nb, warmup_A, T_serial, rho_M, pi_M, out, 0, T, S, dchunk);
        }
        if (dTailStart < T) {
            dim3 grid((quads + 255) / 256, 1, 1);
            forecast4_kernel<10, true><<<grid, block, 0, stream>>>(
                Lpart, bsums, nb, warmup_A, T_serial, rho_M, pi_M, out, dTailStart, T, S, dchunk);
        }
    }
    const int tail = S - quads * 4;
    if (tail > 0) {
        dim3 block(64, 1, 1);
        dim3 grid(1, (T + dchunk - 1) / dchunk, 1);
        forecast_scalar_kernel<10><<<grid, block, 0, stream>>>(
            Lpart, bsums, nb, warmup_A, T_serial, rho_M, pi_M, out, T, S,
            quads * 4, dchunk);
    }
}